// Round 8
// baseline (164.807 us; speedup 1.0000x reference)
//
#include <hip/hip_runtime.h>
#include <cstdint>
#include <cstddef>

#define BB 32
#define NN 4096
#define DD 256
#define KK 16

constexpr int TILE  = 64;             // tokens per block
constexpr int SUB   = 16;             // tokens per sub-tile (LDS-staged)
constexpr int NSUB  = TILE / SUB;     // 4
constexpr int TPBAT = NN / TILE;      // 64 tiles per batch
constexpr int TILES = BB * TPBAT;     // 2048
constexpr int ROWF  = 260;            // padded row stride in floats (256+4)
constexpr float FEPS = 1e-12f;

__device__ __forceinline__ float dot4(float4 a, float4 b) {
  return a.x*b.x + a.y*b.y + a.z*b.z + a.w*b.w;
}
__device__ __forceinline__ float4 f4add(float4 a, float4 b) {
  return make_float4(a.x+b.x, a.y+b.y, a.z+b.z, a.w+b.w);
}

// ---------------------------------------------------------------------------
// Single-pass fused kernel: per 16-token sub-tile staged once in LDS:
//   logits (thread = token-pair x dim-half x k, W shared across the pair)
//   -> softmax (pure shfl) -> outer-product accumulate (wave = k-quad).
// x is read from global EXACTLY ONCE. Reg-staged async staging (no dbuf).
// ---------------------------------------------------------------------------
__global__ __launch_bounds__(256, 8) void fused_kernel(
    const float* __restrict__ x, const int* __restrict__ mask,
    const float* __restrict__ W, const float* __restrict__ bias,
    float* __restrict__ outv, float* __restrict__ outs, int partial_mode)
{
  __shared__ float xs[SUB * ROWF];    // 16.25 KB staged sub-tile (pad-260)
  __shared__ float al[SUB * KK];      // 1 KB assigns

  const int tid  = threadIdx.x;
  const int lane = tid & 63;
  const int wave = tid >> 6;
  const int tp   = tid >> 5;          // token pair 0..7
  const int dc   = (tid >> 4) & 1;    // dim half 0..1
  const int k    = tid & 15;          // cluster 0..15

  const int tile = blockIdx.x;
  const int b    = tile / TPBAT;
  const int n0   = (tile % TPBAT) * TILE;

  const float4* xb4 = reinterpret_cast<const float4*>(x + ((size_t)b*NN + n0)*DD);
  const int*    mb  = mask + (size_t)b*NN + n0;

  const float  bk = bias[k];
  const float* Wh = W + k * DD + dc * 128;     // this thread's W half-row

  // Phase-B persistent state (wave = k-quad, lane = dim-quad)
  float4 acc0 = make_float4(0.f,0.f,0.f,0.f);
  float4 acc1 = acc0, acc2 = acc0, acc3 = acc0, asum = acc0;

  // prologue: stage sub-tile 0
  {
    float4 s0 = xb4[0*256 + tid], s1 = xb4[1*256 + tid],
           s2 = xb4[2*256 + tid], s3 = xb4[3*256 + tid];
    int i;
    i = 0*256 + tid; *reinterpret_cast<float4*>(xs + (i>>6)*ROWF + (i&63)*4) = s0;
    i = 1*256 + tid; *reinterpret_cast<float4*>(xs + (i>>6)*ROWF + (i&63)*4) = s1;
    i = 2*256 + tid; *reinterpret_cast<float4*>(xs + (i>>6)*ROWF + (i&63)*4) = s2;
    i = 3*256 + tid; *reinterpret_cast<float4*>(xs + (i>>6)*ROWF + (i&63)*4) = s3;
  }

#pragma unroll
  for (int st = 0; st < NSUB; ++st) {
    __syncthreads();                       // xs[st] visible

    // issue next sub-tile's global loads now; land them after barrier 3
    float4 n0v, n1v, n2v, n3v;
    if (st < NSUB - 1) {
      const int o = (st + 1) * (SUB * 64);
      n0v = xb4[o + 0*256 + tid]; n1v = xb4[o + 1*256 + tid];
      n2v = xb4[o + 2*256 + tid]; n3v = xb4[o + 3*256 + tid];
    }
    const int mva = mb[st*SUB + 2*tp + 0];
    const int mvb = mb[st*SUB + 2*tp + 1];

    // ---- Phase A: logits for tokens 2tp, 2tp+1 over dim-half dc ----------
    const float* rowA = xs + (2*tp + 0) * ROWF + dc * 128;
    const float* rowB = xs + (2*tp + 1) * ROWF + dc * 128;
    float pa0 = 0.f, pa1 = 0.f, pb0 = 0.f, pb1 = 0.f;
#pragma unroll 2
    for (int j = 0; j < 32; ++j) {
      const float4 wv  = *reinterpret_cast<const float4*>(Wh   + j*4);
      const float4 xva = *reinterpret_cast<const float4*>(rowA + j*4);
      const float4 xvb = *reinterpret_cast<const float4*>(rowB + j*4);
      if (j & 1) { pa1 += dot4(xva, wv); pb1 += dot4(xvb, wv); }
      else       { pa0 += dot4(xva, wv); pb0 += dot4(xvb, wv); }
    }
    float la = pa0 + pa1, lb = pb0 + pb1;
    la += __shfl_xor(la, 16);              // combine dim halves
    lb += __shfl_xor(lb, 16);
    la += bk; lb += bk;

    // softmax over k (16 lanes); logits are small -> no max subtraction
    float ea = __expf(la), eb = __expf(lb);
    float sa = ea, sb = eb;
    sa += __shfl_xor(sa, 1); sb += __shfl_xor(sb, 1);
    sa += __shfl_xor(sa, 2); sb += __shfl_xor(sb, 2);
    sa += __shfl_xor(sa, 4); sb += __shfl_xor(sb, 4);
    sa += __shfl_xor(sa, 8); sb += __shfl_xor(sb, 8);
    const float aa = mva ? ea / sa : 0.0f;
    const float ab = mvb ? eb / sb : 0.0f;
    if (dc == 0) {
      al[(2*tp + 0) * KK + k] = aa;
      al[(2*tp + 1) * KK + k] = ab;
    }
    __syncthreads();                       // al visible

    // ---- Phase B: wave = k-quad, lane = dim-quad, x + al from LDS --------
#pragma unroll 4
    for (int t = 0; t < SUB; ++t) {
      const float4 av = *reinterpret_cast<const float4*>(al + t*KK + 4*wave);
      const float4 xv = *reinterpret_cast<const float4*>(xs + t*ROWF + 4*lane);
      acc0.x += av.x*xv.x; acc0.y += av.x*xv.y; acc0.z += av.x*xv.z; acc0.w += av.x*xv.w;
      acc1.x += av.y*xv.x; acc1.y += av.y*xv.y; acc1.z += av.y*xv.z; acc1.w += av.y*xv.w;
      acc2.x += av.z*xv.x; acc2.y += av.z*xv.y; acc2.z += av.z*xv.z; acc2.w += av.z*xv.w;
      acc3.x += av.w*xv.x; acc3.y += av.w*xv.y; acc3.z += av.w*xv.z; acc3.w += av.w*xv.w;
      asum = f4add(asum, av);
    }

    if (st < NSUB - 1) {
      __syncthreads();                     // all waves done reading xs[st]
      int i;
      i = 0*256 + tid; *reinterpret_cast<float4*>(xs + (i>>6)*ROWF + (i&63)*4) = n0v;
      i = 1*256 + tid; *reinterpret_cast<float4*>(xs + (i>>6)*ROWF + (i&63)*4) = n1v;
      i = 2*256 + tid; *reinterpret_cast<float4*>(xs + (i>>6)*ROWF + (i&63)*4) = n2v;
      i = 3*256 + tid; *reinterpret_cast<float4*>(xs + (i>>6)*ROWF + (i&63)*4) = n3v;
    }
  }

  // ------------- output ----------------------------------------------------
  const int kq = wave * 4;
  if (partial_mode) {
    float4* dst = reinterpret_cast<float4*>(outv + (size_t)tile * KK * DD);
    dst[(kq + 0) * 64 + lane] = acc0;
    dst[(kq + 1) * 64 + lane] = acc1;
    dst[(kq + 2) * 64 + lane] = acc2;
    dst[(kq + 3) * 64 + lane] = acc3;
    if (lane == 0)
      *reinterpret_cast<float4*>(outs + tile * KK + kq) = asum;
  } else {
    float* vb = outv + (size_t)b * KK * DD;
    const float4 aa4[4] = {acc0, acc1, acc2, acc3};
#pragma unroll
    for (int i = 0; i < 4; ++i) {
      float* p = vb + (kq + i) * DD + 4 * lane;
      atomicAdd(p + 0, aa4[i].x);
      atomicAdd(p + 1, aa4[i].y);
      atomicAdd(p + 2, aa4[i].z);
      atomicAdd(p + 3, aa4[i].w);
    }
    if (lane == 0) {
      atomicAdd(&outs[b * KK + kq + 0], asum.x);
      atomicAdd(&outs[b * KK + kq + 1], asum.y);
      atomicAdd(&outs[b * KK + kq + 2], asum.z);
      atomicAdd(&outs[b * KK + kq + 3], asum.w);
    }
  }
}

// ---------------------------------------------------------------------------
// Finalize A (BB*KK blocks x 256 thr): block = (b,k). float4 slice-sum with
// 4 slice-groups x 4 accumulators, LDS combine, ssum by wave butterfly.
// ---------------------------------------------------------------------------
__global__ __launch_bounds__(256) void finalizeA_kernel(
    const float* __restrict__ pv, const float* __restrict__ ps,
    const float* __restrict__ cent, float* __restrict__ vtmp,
    float* __restrict__ ssbuf, int nslice)
{
  const int blk = blockIdx.x;
  const int b   = blk >> 4;
  const int k   = blk & 15;
  const int tid = threadIdx.x;
  const int sg  = tid >> 6;           // slice group 0..3
  const int ld  = tid & 63;           // float4 dim index

  __shared__ float4 cmbA[3][64];

  // ssum: each wave loads 64-strided slices, butterfly -> all lanes
  float pval = 0.f;
  for (int s = ld; s < nslice; s += 64)
    pval += ps[(size_t)(b * nslice + s) * KK + k];
#pragma unroll
  for (int off = 32; off >= 1; off >>= 1) pval += __shfl_xor(pval, off);
  const float ssum = pval;

  // slice sum: slices s == sg (mod 4), 4 independent accumulators
  const float4* pv4 = reinterpret_cast<const float4*>(pv);
  const size_t base = ((size_t)b * nslice * KK + k) * 64 + ld;  // f4 idx, slice 0
  float4 a0 = make_float4(0.f,0.f,0.f,0.f), a1 = a0, a2 = a0, a3 = a0;
  int s = sg;
  for (; s + 12 < nslice; s += 16) {
    a0 = f4add(a0, pv4[base + (size_t)(s     ) * (KK * 64)]);
    a1 = f4add(a1, pv4[base + (size_t)(s +  4) * (KK * 64)]);
    a2 = f4add(a2, pv4[base + (size_t)(s +  8) * (KK * 64)]);
    a3 = f4add(a3, pv4[base + (size_t)(s + 12) * (KK * 64)]);
  }
  for (; s < nslice; s += 4)
    a0 = f4add(a0, pv4[base + (size_t)s * (KK * 64)]);
  float4 tot = f4add(f4add(a0, a1), f4add(a2, a3));

  if (sg > 0) cmbA[sg - 1][ld] = tot;
  __syncthreads();

  if (sg == 0) {
    tot = f4add(tot, f4add(cmbA[0][ld], f4add(cmbA[1][ld], cmbA[2][ld])));
    const float4 cv = reinterpret_cast<const float4*>(cent)[k * 64 + ld];
    float4 v;
    v.x = tot.x - ssum * cv.x;
    v.y = tot.y - ssum * cv.y;
    v.z = tot.z - ssum * cv.z;
    v.w = tot.w - ssum * cv.w;
    reinterpret_cast<float4*>(vtmp)[((size_t)b * KK + k) * 64 + ld] = v;
    float p = dot4(v, v);
#pragma unroll
    for (int off = 32; off >= 1; off >>= 1) p += __shfl_xor(p, off);
    if (ld == 0) ssbuf[blk] = p;
  }
}

// ---------------------------------------------------------------------------
// Finalize B (BB blocks x 1024 thr): intra-cluster + global L2 normalize.
// ---------------------------------------------------------------------------
__global__ __launch_bounds__(1024) void finalizeB_kernel(
    const float* __restrict__ vtmp, const float* __restrict__ ssbuf,
    float* __restrict__ out)
{
  const int b    = blockIdx.x;
  const int tid  = threadIdx.x;
  const int d    = tid & 255;
  const int kq   = tid >> 8;        // 0..3
  const int lane = tid & 63;
  const int w    = tid >> 6;        // 0..15

  __shared__ float redB[16];
  __shared__ float gsh;

  float u[4];
  float p2 = 0.f;
#pragma unroll
  for (int kk = 0; kk < 4; ++kk) {
    const int k = kq * 4 + kk;
    const float rk = 1.0f / fmaxf(sqrtf(ssbuf[b * KK + k]), FEPS);
    u[kk] = vtmp[((size_t)b * KK + k) * DD + d] * rk;
    p2 += u[kk] * u[kk];
  }
#pragma unroll
  for (int off = 32; off >= 1; off >>= 1) p2 += __shfl_xor(p2, off);
  if (lane == 0) redB[w] = p2;
  __syncthreads();

  if (tid == 0) {
    float g = 0.f;
#pragma unroll
    for (int i = 0; i < 16; ++i) g += redB[i];
    gsh = 1.0f / fmaxf(sqrtf(g), FEPS);
  }
  __syncthreads();

  const float g = gsh;
#pragma unroll
  for (int kk = 0; kk < 4; ++kk) {
    const int k = kq * 4 + kk;
    out[(size_t)b * KK * DD + k * DD + d] = u[kk] * g;
  }
}

extern "C" void kernel_launch(void* const* d_in, const int* in_sizes, int n_in,
                              void* d_out, int out_size, void* d_ws, size_t ws_size,
                              hipStream_t stream) {
  const float* x    = (const float*)d_in[0];
  const int*   mask = (const int*)d_in[1];
  const float* W    = (const float*)d_in[2];
  const float* bias = (const float*)d_in[3];
  const float* cent = (const float*)d_in[4];
  float* out = (float*)d_out;

  const size_t vtmpN = (size_t)BB * KK * DD;
  const size_t ssN   = (size_t)BB * KK;
  const size_t need  = ((size_t)TILES * KK * DD + (size_t)TILES * KK
                        + vtmpN + ssN) * sizeof(float);

  if (ws_size >= need) {
    float* pv    = (float*)d_ws;
    float* ps    = pv + (size_t)TILES * KK * DD;
    float* vtmp  = ps + (size_t)TILES * KK;
    float* ssbuf = vtmp + vtmpN;
    fused_kernel<<<TILES, 256, 0, stream>>>(x, mask, W, bias, pv, ps, 1);
    finalizeA_kernel<<<BB * KK, 256, 0, stream>>>(pv, ps, cent, vtmp, ssbuf, TPBAT);
    finalizeB_kernel<<<BB, 1024, 0, stream>>>(vtmp, ssbuf, out);
  } else {
    float* vacc  = (float*)d_ws;                 // [BB][KK][DD]
    float* sacc  = vacc + vtmpN;                 // [BB][KK]
    float* vtmp  = sacc + ssN;
    float* ssbuf = vtmp + vtmpN;
    hipMemsetAsync(d_ws, 0, (vtmpN + ssN) * sizeof(float), stream);
    fused_kernel<<<TILES, 256, 0, stream>>>(x, mask, W, bias, vacc, sacc, 0);
    finalizeA_kernel<<<BB * KK, 256, 0, stream>>>(vacc, sacc, cent, vtmp, ssbuf, 1);
    finalizeB_kernel<<<BB, 1024, 0, stream>>>(vtmp, ssbuf, out);
  }
}